// Round 1
// baseline (137.087 us; speedup 1.0000x reference)
//
#include <hip/hip_runtime.h>
#include <cstdint>

#define TOK 2048
#define EMB 768
#define WIN 64

typedef __attribute__((ext_vector_type(8))) __bf16 bf16x8;
typedef __attribute__((ext_vector_type(4))) float f32x4;

static __device__ __forceinline__ unsigned short f2bf(float f) {
  uint32_t x = __float_as_uint(f);
  uint32_t r = (x + 0x7fffu + ((x >> 16) & 1u)) >> 16;  // RNE
  return (unsigned short)r;
}
static __device__ __forceinline__ float bf2f(unsigned short u) {
  return __uint_as_float(((uint32_t)u) << 16);
}

static __device__ __forceinline__ void gload_lds16(const void* g, void* l) {
  __builtin_amdgcn_global_load_lds(
      (const __attribute__((address_space(1))) uint32_t*)g,
      (__attribute__((address_space(3))) uint32_t*)l, 16, 0, 0);
}

// ---------------- prep: inputs -> bf16 hi/lo ----------------
__global__ __launch_bounds__(256) void cvt_inputs(
    const float* __restrict__ a0, const float* __restrict__ a1,
    const float* __restrict__ a2, unsigned short* __restrict__ hi,
    unsigned short* __restrict__ lo) {
  const int64_t NE4 = (int64_t)TOK * EMB / 4;  // float4 per input
  int64_t i = (int64_t)blockIdx.x * blockDim.x + threadIdx.x;
  if (i >= 3 * NE4) return;
  int which = (int)(i / NE4);
  int64_t loc = i - (int64_t)which * NE4;
  const float4* src = (const float4*)(which == 0 ? a0 : which == 1 ? a1 : a2);
  float4 x = src[loc];
  float fx[4] = {x.x, x.y, x.z, x.w};
  ushort4 h, l;
  unsigned short hh[4], ll[4];
#pragma unroll
  for (int j = 0; j < 4; ++j) {
    hh[j] = f2bf(fx[j]);
    ll[j] = f2bf(fx[j] - bf2f(hh[j]));
  }
  h.x = hh[0]; h.y = hh[1]; h.z = hh[2]; h.w = hh[3];
  l.x = ll[0]; l.y = ll[1]; l.z = ll[2]; l.w = ll[3];
  ((ushort4*)hi)[i] = h;
  ((ushort4*)lo)[i] = l;
}

// ---------------- prep: weights -> transposed bf16 hi/lo ----------------
// WT[d][e] = W[e][d]; so B-fragments are contiguous along K(=e).
__global__ void cvt_wT(const float* __restrict__ w0, const float* __restrict__ w1,
                       const float* __restrict__ w2,
                       unsigned short* __restrict__ hiT,
                       unsigned short* __restrict__ loT) {
  __shared__ float t[32][33];
  const int z = blockIdx.z;
  const float* w = (z == 0) ? w0 : (z == 1) ? w1 : w2;
  const int d0 = blockIdx.x * 32, e0 = blockIdx.y * 32;
  const int tx = threadIdx.x, ty = threadIdx.y;  // (32,8)
#pragma unroll
  for (int r = 0; r < 4; ++r)
    t[ty + r * 8][tx] = w[(size_t)(e0 + ty + r * 8) * EMB + d0 + tx];
  __syncthreads();
#pragma unroll
  for (int r = 0; r < 4; ++r) {
    const int dl = ty + r * 8, el = tx;
    const float f = t[el][dl];  // = W[e0+el][d0+dl]
    const size_t o = (size_t)z * EMB * EMB + (size_t)(d0 + dl) * EMB + e0 + el;
    unsigned short h = f2bf(f);
    hiT[o] = h;
    loT[o] = f2bf(f - bf2f(h));
  }
}

// ---------------- projections: split-bf16 MFMA GEMM ----------------
// C[z] = A[z] @ W[z], fp32-accurate via 3 bf16 terms:
//   Ahi@Bhi (ph0) + Alo@Bhi (ph1) + Ahi@Blo (ph2), K=768 each.
// m97 structure: 128x128 tile, BK=32, 4 waves (2x2), global_load_lds w=16.
__global__ __launch_bounds__(256) void proj_gemm(
    const unsigned short* __restrict__ Ahi, const unsigned short* __restrict__ Alo,
    const unsigned short* __restrict__ WThi, const unsigned short* __restrict__ WTlo,
    float* __restrict__ outkvq) {
  const int z = blockIdx.z;
  const int bn0 = blockIdx.x * 128;  // output col (D)
  const int bm0 = blockIdx.y * 128;  // output row (token)
  const int tid = threadIdx.x, lane = tid & 63, w = tid >> 6;
  const int wr = w >> 1, wc = w & 1;

  __shared__ unsigned short lA[128 * 32];
  __shared__ unsigned short lB[128 * 32];

  const unsigned short* Ah = Ahi + (size_t)z * TOK * EMB;
  const unsigned short* Al = Alo + (size_t)z * TOK * EMB;
  const unsigned short* Bh = WThi + (size_t)z * EMB * EMB;
  const unsigned short* Bl = WTlo + (size_t)z * EMB * EMB;

  f32x4 acc[4][4] = {};

  const int sr = lane >> 2;          // row within 16-row chunk
  const int sk = (lane & 3) * 8;     // k element offset (16B)

  for (int ph = 0; ph < 3; ++ph) {
    const unsigned short* Asrc = (ph == 1) ? Al : Ah;
    const unsigned short* Bsrc = (ph == 2) ? Bl : Bh;
    for (int kk = 0; kk < EMB; kk += 32) {
      __syncthreads();  // previous compute done before overwrite
#pragma unroll
      for (int c = 0; c < 2; ++c) {
        const int chunk = w * 2 + c;            // 0..7, 16 rows each
        const int row = chunk * 16 + sr;
        gload_lds16(Asrc + (size_t)(bm0 + row) * EMB + kk + sk,
                    (char*)lA + chunk * 1024);
        gload_lds16(Bsrc + (size_t)(bn0 + row) * EMB + kk + sk,
                    (char*)lB + chunk * 1024);
      }
      __syncthreads();  // staging visible (vmcnt(0) drained here)

      bf16x8 af[4], bfr[4];
#pragma unroll
      for (int m = 0; m < 4; ++m)
        af[m] = *(const bf16x8*)&lA[(wr * 64 + m * 16 + (lane & 15)) * 32 +
                                    (lane >> 4) * 8];
#pragma unroll
      for (int n = 0; n < 4; ++n)
        bfr[n] = *(const bf16x8*)&lB[(wc * 64 + n * 16 + (lane & 15)) * 32 +
                                     (lane >> 4) * 8];
#pragma unroll
      for (int m = 0; m < 4; ++m)
#pragma unroll
        for (int n = 0; n < 4; ++n)
          acc[m][n] = __builtin_amdgcn_mfma_f32_16x16x32_bf16(af[m], bfr[n],
                                                              acc[m][n], 0, 0, 0);
    }
  }

  // epilogue: C/D layout col=lane&15, row=(lane>>4)*4+reg (m89-verified)
  float* C = outkvq + (size_t)z * TOK * EMB;
#pragma unroll
  for (int m = 0; m < 4; ++m) {
    const int row = bm0 + wr * 64 + m * 16 + (lane >> 4) * 4;
#pragma unroll
    for (int n = 0; n < 4; ++n) {
      const int col = bn0 + wc * 64 + n * 16 + (lane & 15);
#pragma unroll
      for (int r = 0; r < 4; ++r)
        C[(size_t)(row + r) * EMB + col] = acc[m][n][r];
    }
  }
}

// ---------------- sliding-window attention (fp32) ----------------
// 8 queries/block, window union U<=136 keys. Scores: wave-per-key dot +
// shuffle reduce. Softmax with -1e30 masking. PV: d-parallel. out /= (sum*L).
__global__ __launch_bounds__(256) void attn(const float* __restrict__ kf,
                                            const float* __restrict__ vf,
                                            const float* __restrict__ qf,
                                            float* __restrict__ out) {
  const int t0 = blockIdx.x * 8;
  const int tid = threadIdx.x, lane = tid & 63, w = tid >> 6;
  __shared__ float q_s[8][EMB];
  __shared__ float sc[8][144];
  __shared__ float rcpb[8];

  const int start0 = max(0, t0 - WIN);
  const int U = min(TOK, t0 + 7 + WIN + 1) - start0;

  // phase 0: q -> LDS (float4), scores init to -1e30
  for (int i = tid; i < 8 * EMB / 4; i += 256) {
    const int row = i / (EMB / 4);
    const int c4 = i - row * (EMB / 4);
    ((float4*)&q_s[row][0])[c4] =
        ((const float4*)(qf + (size_t)(t0 + row) * EMB))[c4];
  }
  for (int i = tid; i < 8 * 144; i += 256) ((float*)sc)[i] = -1e30f;
  __syncthreads();

  // phase 1: scores. Each wave owns keys jl = w, w+4, ...
  {
    float qr[8][12];
#pragma unroll
    for (int qi = 0; qi < 8; ++qi)
#pragma unroll
      for (int i = 0; i < 12; ++i) qr[qi][i] = q_s[qi][lane + 64 * i];

    const int tq = t0 + lane;  // lanes 0..7 write query 'lane'
    const int sL = max(0, tq - WIN);
    const int eL = min(TOK, tq + WIN + 1);

    for (int jl = w; jl < U; jl += 4) {
      const int j = start0 + jl;
      float kr[12];
#pragma unroll
      for (int i = 0; i < 12; ++i)
        kr[i] = kf[(size_t)j * EMB + lane + 64 * i];
      float dd[8];
#pragma unroll
      for (int qi = 0; qi < 8; ++qi) {
        float s = 0.f;
#pragma unroll
        for (int i = 0; i < 12; ++i) s = fmaf(qr[qi][i], kr[i], s);
        dd[qi] = s;
      }
#pragma unroll
      for (int qi = 0; qi < 8; ++qi) {
        float v = dd[qi];
#pragma unroll
        for (int off = 32; off > 0; off >>= 1) v += __shfl_xor(v, off);
        dd[qi] = v;
      }
      if (lane < 8 && j >= sL && j < eL) {
        float val = dd[0];
        val = (lane == 1) ? dd[1] : val;
        val = (lane == 2) ? dd[2] : val;
        val = (lane == 3) ? dd[3] : val;
        val = (lane == 4) ? dd[4] : val;
        val = (lane == 5) ? dd[5] : val;
        val = (lane == 6) ? dd[6] : val;
        val = (lane == 7) ? dd[7] : val;
        sc[lane][jl] = val * 0.03608439182435161f;  // 768^-0.5
      }
    }
  }
  __syncthreads();

  // phase 2: per-query softmax over 144 slots (invalid = -1e30 -> p = 0)
#pragma unroll
  for (int s2 = 0; s2 < 2; ++s2) {
    const int qi = w * 2 + s2;
    float a = sc[qi][lane];
    float b = sc[qi][lane + 64];
    float c = (lane < 16) ? sc[qi][lane + 128] : -1e30f;
    float m = fmaxf(a, fmaxf(b, c));
#pragma unroll
    for (int off = 32; off > 0; off >>= 1) m = fmaxf(m, __shfl_xor(m, off));
    const float e0 = __expf(a - m), e1 = __expf(b - m);
    const float e2 = (lane < 16) ? __expf(c - m) : 0.f;
    sc[qi][lane] = e0;
    sc[qi][lane + 64] = e1;
    if (lane < 16) sc[qi][lane + 128] = e2;
    float sum = e0 + e1 + e2;
#pragma unroll
    for (int off = 32; off > 0; off >>= 1) sum += __shfl_xor(sum, off);
    if (lane == 0) {
      const int tq = t0 + qi;
      const float L = (float)(min(TOK, tq + WIN + 1) - max(0, tq - WIN));
      rcpb[qi] = 1.0f / (sum * L);
    }
  }
  __syncthreads();

  // phase 3: PV, thread owns d = tid, tid+256, tid+512
  float acc[8][3] = {};
  for (int jl = 0; jl < U; ++jl) {
    const size_t j = (size_t)(start0 + jl);
    float p[8];
#pragma unroll
    for (int qi = 0; qi < 8; ++qi) p[qi] = sc[qi][jl];
#pragma unroll
    for (int i = 0; i < 3; ++i) {
      const float vv = vf[j * EMB + tid + i * 256];
#pragma unroll
      for (int qi = 0; qi < 8; ++qi) acc[qi][i] = fmaf(p[qi], vv, acc[qi][i]);
    }
  }
#pragma unroll
  for (int qi = 0; qi < 8; ++qi) {
    const float r = rcpb[qi];
#pragma unroll
    for (int i = 0; i < 3; ++i)
      out[(size_t)(t0 + qi) * EMB + tid + i * 256] = acc[qi][i] * r;
  }
}

extern "C" void kernel_launch(void* const* d_in, const int* in_sizes, int n_in,
                              void* d_out, int out_size, void* d_ws, size_t ws_size,
                              hipStream_t stream) {
  const float* key = (const float*)d_in[0];
  const float* value = (const float*)d_in[1];
  const float* query = (const float*)d_in[2];
  const float* Wk = (const float*)d_in[3];
  const float* Wv = (const float*)d_in[4];
  const float* Wq = (const float*)d_in[5];

  // ws layout (44.8 MB total):
  //   Ahi[3][2048*768] bf16 | Alo same | WThi[3][768*768] bf16 | WTlo same
  //   | kvq[3][2048*768] f32
  char* ws = (char*)d_ws;
  const size_t NA = (size_t)3 * TOK * EMB;
  const size_t NW = (size_t)3 * EMB * EMB;
  unsigned short* Ahi = (unsigned short*)ws;
  unsigned short* Alo = Ahi + NA;
  unsigned short* WThi = Alo + NA;
  unsigned short* WTlo = WThi + NW;
  float* kvq = (float*)(WTlo + NW);
  float* kf = kvq;
  float* vf = kvq + (size_t)TOK * EMB;
  float* qf = kvq + (size_t)2 * TOK * EMB;
  float* out = (float*)d_out;

  cvt_inputs<<<(3 * TOK * EMB / 4 + 255) / 256, 256, 0, stream>>>(
      key, value, query, Ahi, Alo);
  cvt_wT<<<dim3(EMB / 32, EMB / 32, 3), dim3(32, 8), 0, stream>>>(
      Wk, Wv, Wq, WThi, WTlo);
  proj_gemm<<<dim3(EMB / 128, TOK / 128, 3), 256, 0, stream>>>(
      Ahi, Alo, WThi, WTlo, kvq);
  attn<<<TOK / 8, 256, 0, stream>>>(kf, vf, qf, out);
}